// Round 7
// baseline (736.406 us; speedup 1.0000x reference)
//
#include <hip/hip_runtime.h>

// ---------------------------------------------------------------------------
// GraphSAGE 3-layer, bf16 pipeline.
// Round 7 (= round 6 with compile fix: nt-store needs ext_vector_type).
//   - aggregation: feature slice (64B) per XCD, persistent 1024-block grid
//     (all blocks co-resident -> bid&7 == XCD stable), 4-lane/16B edge groups
//     (1KB per wave-load), nt col loads + nt agg stores to keep the 3.2MB
//     gather set resident in each XCD's 4MB L2.
//   - CSR count/fill: dst-range per XCD, persistent grid, nt streams.
//   - layer 2 keeps agg(h@Wl2) reorder (64-dim gathers).
// ---------------------------------------------------------------------------

typedef short bf16x8 __attribute__((ext_vector_type(8)));
typedef float f32x4 __attribute__((ext_vector_type(4)));
typedef unsigned u32x4 __attribute__((ext_vector_type(4)));

__device__ __forceinline__ unsigned short f2bf(float f) {
    unsigned int b = __float_as_uint(f);
    b += 0x7fffu + ((b >> 16) & 1u);
    return (unsigned short)(b >> 16);
}
__device__ __forceinline__ float bflo(unsigned int u) { return __uint_as_float(u << 16); }
__device__ __forceinline__ float bfhi(unsigned int u) { return __uint_as_float(u & 0xffff0000u); }

__device__ __forceinline__ void gload_lds16(const void* g, void* l) {
    __builtin_amdgcn_global_load_lds(
        (const __attribute__((address_space(1))) void*)g,
        (__attribute__((address_space(3))) void*)l, 16, 0, 0);
}

// ---------------- CSR build (persistent, XCD dst-range partitioned) --------
__global__ __launch_bounds__(256) void count_deg_part_kernel(
        const int* __restrict__ ei, int* __restrict__ deg, int E, int n) {
    const int part = blockIdx.x & 7;
    const int cb = blockIdx.x >> 3;                     // 0..127
    const int lo = (int)(((long long)part * n) >> 3);
    const int hi = (int)(((long long)(part + 1) * n) >> 3);
    for (int e = cb * 256 + threadIdx.x; e < E; e += 128 * 256) {
        int d = __builtin_nontemporal_load(ei + E + e);
        if (d >= lo && d < hi) atomicAdd(&deg[d], 1);
    }
}

__global__ __launch_bounds__(1024) void scan1_kernel(
        const int* __restrict__ deg, int* __restrict__ incl, int* __restrict__ bsum, int n) {
    __shared__ int wsum[16];
    __shared__ int woff[16];
    const int tid = threadIdx.x, lane = tid & 63, wid = tid >> 6;
    int i = blockIdx.x * 1024 + tid;
    int x = (i < n) ? deg[i] : 0;
    #pragma unroll
    for (int off = 1; off < 64; off <<= 1) {
        int t = __shfl_up(x, off, 64);
        if (lane >= off) x += t;
    }
    if (lane == 63) wsum[wid] = x;
    __syncthreads();
    if (tid == 0) {
        int s = 0;
        #pragma unroll
        for (int w = 0; w < 16; ++w) { woff[w] = s; s += wsum[w]; }
        bsum[blockIdx.x] = s;
    }
    __syncthreads();
    if (i < n) incl[i] = x + woff[wid];
}

__global__ void scan2_kernel(int* __restrict__ bsum, int nb) {
    int lane = threadIdx.x;
    int v = (lane < nb) ? bsum[lane] : 0;
    int x = v;
    #pragma unroll
    for (int off = 1; off < 64; off <<= 1) {
        int t = __shfl_up(x, off, 64);
        if (lane >= off) x += t;
    }
    if (lane < nb) bsum[lane] = x - v;   // exclusive
}

__global__ void scan3_kernel(const int* __restrict__ incl, const int* __restrict__ bsum,
                             int* __restrict__ row_ptr, int* __restrict__ cursor, int n) {
    int i = blockIdx.x * blockDim.x + threadIdx.x;
    if (i == 0) { row_ptr[0] = 0; cursor[0] = 0; }
    if (i < n) {
        int v = incl[i] + bsum[i >> 10];
        row_ptr[i + 1] = v;
        if (i + 1 < n) cursor[i + 1] = v;
    }
}

__global__ __launch_bounds__(256) void fill_csr_part_kernel(
        const int* __restrict__ ei, int* __restrict__ cursor, int* __restrict__ col,
        int E, int n) {
    const int part = blockIdx.x & 7;
    const int cb = blockIdx.x >> 3;
    const int lo = (int)(((long long)part * n) >> 3);
    const int hi = (int)(((long long)(part + 1) * n) >> 3);
    for (int e = cb * 256 + threadIdx.x; e < E; e += 128 * 256) {
        int d = __builtin_nontemporal_load(ei + E + e);
        if (d >= lo && d < hi) {
            int s = __builtin_nontemporal_load(ei + e);
            int pos = atomicAdd(&cursor[d], 1);
            __builtin_nontemporal_store(s, &col[pos]);
        }
    }
}

// ---------------- converts ----------------
__global__ void cvt_bf16_kernel(const float* __restrict__ x, unsigned short* __restrict__ y, int n4) {
    int i = blockIdx.x * blockDim.x + threadIdx.x;
    if (i < n4) {
        float4 v = ((const float4*)x)[i];
        ushort4 o;
        o.x = f2bf(v.x); o.y = f2bf(v.y); o.z = f2bf(v.z); o.w = f2bf(v.w);
        ((ushort4*)y)[i] = o;
    }
}

__global__ void build_bt_kernel(const float* __restrict__ Wl, const float* __restrict__ Wr,
                                unsigned short* __restrict__ BT, int N) {
    int id = blockIdx.x * blockDim.x + threadIdx.x;
    if (id >= N * 512) return;
    int k = id / N;
    int n = id - k * N;
    float v = (k < 256) ? Wl[(size_t)k * N + n] : Wr[(size_t)(k - 256) * N + n];
    BT[(size_t)n * 512 + k] = f2bf(v);
}

__global__ void build_bt1_kernel(const float* __restrict__ W, unsigned short* __restrict__ BT, int N) {
    int id = blockIdx.x * blockDim.x + threadIdx.x;
    if (id >= N * 256) return;
    int k = id / N;
    int n = id - k * N;
    BT[(size_t)n * 256 + k] = f2bf(W[(size_t)k * N + n]);
}

// ---------------- persistent XCD-sliced aggregation ----------------
// Slice = 32 features (64B = one L2 line). Grid = 1024 blocks (4/CU, all
// co-resident -> bid&7 == XCD, stable). Per edge: 4 lanes x 16B. Wave = one
// node at a time, 16 edge groups in flight; shfl_xor reduce over groups.
template<int DIM, int SLICES, bool OUT_BF16>
__global__ __launch_bounds__(256) void aggregate_persist_kernel(
        const unsigned short* __restrict__ h, const int* __restrict__ row_ptr,
        const int* __restrict__ col, void* __restrict__ agg, int n) {
    constexpr int F = DIM / SLICES;        // 32 features per slice
    constexpr int BPS = 8 / SLICES;        // XCD sub-chunks sharing a slice
    const int bid = blockIdx.x;            // grid = 1024
    const int xcd = bid & 7;
    const int slice = xcd / BPS;
    const int sub = xcd % BPS;
    const int chunk = bid >> 3;            // 0..127
    const int wid = threadIdx.x >> 6;
    const int lane = threadIdx.x & 63;
    const int g = lane >> 2;               // edge group 0..15
    const int fo = slice * F + (lane & 3) * 8;  // feature offset (elems)
    const int wps = BPS * 128 * 4;         // waves per slice (= node stride)
    const int w0 = ((sub * 128 + chunk) * 4) + wid;

    for (int node = w0; node < n; node += wps) {
        const int start = row_ptr[node], end = row_ptr[node + 1];
        float a[8] = {0.f, 0.f, 0.f, 0.f, 0.f, 0.f, 0.f, 0.f};
        for (int eb = start; eb < end; eb += 16) {
            int e = eb + g;
            if (e < end) {
                int c = __builtin_nontemporal_load(col + e);
                uint4 v = *(const uint4*)(h + (size_t)c * DIM + fo);
                a[0] += bflo(v.x); a[1] += bfhi(v.x);
                a[2] += bflo(v.y); a[3] += bfhi(v.y);
                a[4] += bflo(v.z); a[5] += bfhi(v.z);
                a[6] += bflo(v.w); a[7] += bfhi(v.w);
            }
        }
        #pragma unroll
        for (int m = 4; m <= 32; m <<= 1)
            #pragma unroll
            for (int i = 0; i < 8; ++i) a[i] += __shfl_xor(a[i], m, 64);
        int d = end - start;
        float inv = 1.0f / (float)(d > 1 ? d : 1);
        if (lane < 4) {
            if (OUT_BF16) {
                u32x4 o;
                o.x = (unsigned)f2bf(a[0] * inv) | ((unsigned)f2bf(a[1] * inv) << 16);
                o.y = (unsigned)f2bf(a[2] * inv) | ((unsigned)f2bf(a[3] * inv) << 16);
                o.z = (unsigned)f2bf(a[4] * inv) | ((unsigned)f2bf(a[5] * inv) << 16);
                o.w = (unsigned)f2bf(a[6] * inv) | ((unsigned)f2bf(a[7] * inv) << 16);
                __builtin_nontemporal_store(o,
                    (u32x4*)((unsigned short*)agg + (size_t)node * DIM + fo));
            } else {
                float* dst = (float*)agg + (size_t)node * DIM + fo;
                f32x4 o0 = {a[0] * inv, a[1] * inv, a[2] * inv, a[3] * inv};
                f32x4 o1 = {a[4] * inv, a[5] * inv, a[6] * inv, a[7] * inv};
                __builtin_nontemporal_store(o0, (f32x4*)dst);
                __builtin_nontemporal_store(o1, (f32x4*)(dst + 4));
            }
        }
    }
}

// ---------------- fused MFMA GEMM ----------------
// C = [A0|A1](M x NKS*32) @ BT^T (+bias) (+add) (+relu); BT is [Nc'][NKS*32] bf16.
// A rows are always 256-wide. BM=128, BN=NT*32, BK=32; 4 waves (2x2).
template<int NKS, int NT, bool RELU, bool OUT_BF16, bool HAS_BIAS, bool HAS_ADD>
__global__ __launch_bounds__(256) void gemm_mfma_kernel(
        const unsigned short* __restrict__ A0, const unsigned short* __restrict__ A1,
        const unsigned short* __restrict__ BT, const float* __restrict__ bias,
        const float* __restrict__ add, void* __restrict__ Cout, int M, int Nc) {
    constexpr int BN = NT * 32;
    constexpr int KB = NKS * 32;           // BT row stride (elems)
    __shared__ unsigned short As[128 * 32];
    __shared__ unsigned short Bs[BN * 32];
    const int tid = threadIdx.x;
    const int lane = tid & 63;
    const int wid = tid >> 6;
    const int wr = wid >> 1, wc = wid & 1;
    const int row0 = blockIdx.x * 128;
    const int col0 = blockIdx.y * BN;

    f32x4 acc[4][NT];
    #pragma unroll
    for (int i = 0; i < 4; ++i)
        #pragma unroll
        for (int j = 0; j < NT; ++j) acc[i][j] = (f32x4){0.f, 0.f, 0.f, 0.f};

    const int rA = tid >> 2;
    const int kc = (tid & 3) * 8;

    for (int ks = 0; ks < NKS; ++ks) {
        const unsigned short* Asrc = (NKS == 16) ? (ks < 8 ? A0 : A1) : A0;
        const int ka = (NKS == 16) ? ((ks & 7) * 32) : (ks * 32);
        #pragma unroll
        for (int i = 0; i < 2; ++i) {
            const unsigned short* g = Asrc + (size_t)(row0 + rA + i * 64) * 256 + ka + kc;
            gload_lds16(g, As + (size_t)i * 2048 + tid * 8);
        }
        #pragma unroll
        for (int i = 0; i < NT / 2; ++i) {
            const unsigned short* g = BT + (size_t)(col0 + rA + i * 64) * KB + ks * 32 + kc;
            gload_lds16(g, Bs + (size_t)i * 2048 + tid * 8);
        }
        __syncthreads();

        bf16x8 a[4], b[NT];
        #pragma unroll
        for (int tm = 0; tm < 4; ++tm)
            a[tm] = *(const bf16x8*)&As[(wr * 64 + tm * 16 + (lane & 15)) * 32 + (lane >> 4) * 8];
        #pragma unroll
        for (int tn = 0; tn < NT; ++tn)
            b[tn] = *(const bf16x8*)&Bs[(wc * NT * 16 + tn * 16 + (lane & 15)) * 32 + (lane >> 4) * 8];
        #pragma unroll
        for (int tm = 0; tm < 4; ++tm)
            #pragma unroll
            for (int tn = 0; tn < NT; ++tn)
                acc[tm][tn] = __builtin_amdgcn_mfma_f32_16x16x32_bf16(a[tm], b[tn], acc[tm][tn], 0, 0, 0);
        __syncthreads();
    }

    const int cb = col0 + wc * NT * 16;
    #pragma unroll
    for (int tn = 0; tn < NT; ++tn) {
        int colg = cb + tn * 16 + (lane & 15);
        float bv = HAS_BIAS ? bias[colg] : 0.f;
        #pragma unroll
        for (int tm = 0; tm < 4; ++tm) {
            #pragma unroll
            for (int r = 0; r < 4; ++r) {
                int row = row0 + wr * 64 + tm * 16 + (lane >> 4) * 4 + r;
                if (row < M) {
                    float v = acc[tm][tn][r] + bv;
                    if (HAS_ADD) v += add[(size_t)row * Nc + colg];
                    if (RELU) v = fmaxf(v, 0.f);
                    if (OUT_BF16)
                        ((unsigned short*)Cout)[(size_t)row * Nc + colg] = f2bf(v);
                    else
                        ((float*)Cout)[(size_t)row * Nc + colg] = v;
                }
            }
        }
    }
}

extern "C" void kernel_launch(void* const* d_in, const int* in_sizes, int n_in,
                              void* d_out, int out_size, void* d_ws, size_t ws_size,
                              hipStream_t stream) {
    const float* x   = (const float*)d_in[0];
    const int*   ei  = (const int*)d_in[1];
    const float* Wl0 = (const float*)d_in[2];
    const float* Wr0 = (const float*)d_in[3];
    const float* b0  = (const float*)d_in[4];
    const float* Wl1 = (const float*)d_in[5];
    const float* Wr1 = (const float*)d_in[6];
    const float* b1  = (const float*)d_in[7];
    const float* Wl2 = (const float*)d_in[8];
    const float* Wr2 = (const float*)d_in[9];
    const float* b2  = (const float*)d_in[10];
    float* out = (float*)d_out;

    const int Nn = in_sizes[0] / 256;          // 50000
    const int E  = in_sizes[1] / 2;            // 800000
    const int Mpad = ((Nn + 127) / 128) * 128; // 50048
    const int nb = (Nn + 1023) / 1024;         // scan blocks (49)

    char* ws = (char*)d_ws;
    size_t off = 0;
    auto take = [&](size_t bytes) -> void* {
        void* p = (void*)(ws + off);
        off += (bytes + 255) & ~(size_t)255;
        return p;
    };
    int* deg     = (int*)take((size_t)Nn * 4);
    int* incl    = (int*)take((size_t)Nn * 4);
    int* bsum    = (int*)take((size_t)64 * 4);
    int* row_ptr = (int*)take((size_t)(Nn + 1) * 4);
    int* cursor  = (int*)take((size_t)Nn * 4);
    int* col     = (int*)take((size_t)E * 4);
    unsigned short* xb  = (unsigned short*)take((size_t)Mpad * 256 * 2);
    unsigned short* h1  = (unsigned short*)take((size_t)Mpad * 256 * 2);
    unsigned short* h2  = (unsigned short*)take((size_t)Mpad * 256 * 2);
    unsigned short* h3  = (unsigned short*)take((size_t)Mpad * 256 * 2);
    unsigned short* p2  = (unsigned short*)take((size_t)Mpad * 64 * 2);
    float* aggp = (float*)take((size_t)Mpad * 64 * 4);
    unsigned short* BT0  = (unsigned short*)take((size_t)256 * 512 * 2);
    unsigned short* BT1  = (unsigned short*)take((size_t)256 * 512 * 2);
    unsigned short* BT2l = (unsigned short*)take((size_t)64 * 256 * 2);
    unsigned short* BT2r = (unsigned short*)take((size_t)64 * 256 * 2);
    (void)ws_size; (void)n_in; (void)out_size;

    // ---- CSR build (persistent, XCD dst-partitioned) ----
    hipMemsetAsync(deg, 0, (size_t)Nn * 4, stream);
    count_deg_part_kernel<<<1024, 256, 0, stream>>>(ei, deg, E, Nn);
    scan1_kernel<<<nb, 1024, 0, stream>>>(deg, incl, bsum, Nn);
    scan2_kernel<<<1, 64, 0, stream>>>(bsum, nb);
    scan3_kernel<<<(Nn + 255) / 256, 256, 0, stream>>>(incl, bsum, row_ptr, cursor, Nn);
    fill_csr_part_kernel<<<1024, 256, 0, stream>>>(ei, cursor, col, E, Nn);

    // ---- converts ----
    cvt_bf16_kernel<<<(Nn * 64 + 255) / 256, 256, 0, stream>>>(x, xb, Nn * 64);
    build_bt_kernel<<<(256 * 512 + 255) / 256, 256, 0, stream>>>(Wl0, Wr0, BT0, 256);
    build_bt_kernel<<<(256 * 512 + 255) / 256, 256, 0, stream>>>(Wl1, Wr1, BT1, 256);
    build_bt1_kernel<<<(64 * 256 + 255) / 256, 256, 0, stream>>>(Wl2, BT2l, 64);
    build_bt1_kernel<<<(64 * 256 + 255) / 256, 256, 0, stream>>>(Wr2, BT2r, 64);

    const int gx = Mpad / 128;

    // ---- layer 0 ----
    aggregate_persist_kernel<256, 8, true><<<1024, 256, 0, stream>>>(xb, row_ptr, col, h1, Nn);
    gemm_mfma_kernel<16, 4, true, true, true, false><<<dim3(gx, 2), 256, 0, stream>>>(
        h1, xb, BT0, b0, nullptr, h2, Nn, 256);
    // ---- layer 1 ----
    aggregate_persist_kernel<256, 8, true><<<1024, 256, 0, stream>>>(h2, row_ptr, col, h1, Nn);
    gemm_mfma_kernel<16, 4, true, true, true, false><<<dim3(gx, 2), 256, 0, stream>>>(
        h1, h2, BT1, b1, nullptr, h3, Nn, 256);
    // ---- layer 2: agg(h3)@Wl2 == agg(h3@Wl2) ----
    gemm_mfma_kernel<8, 2, false, true, false, false><<<dim3(gx, 1), 256, 0, stream>>>(
        h3, nullptr, BT2l, nullptr, nullptr, p2, Nn, 64);
    aggregate_persist_kernel<64, 2, false><<<1024, 256, 0, stream>>>(p2, row_ptr, col, aggp, Nn);
    gemm_mfma_kernel<8, 2, false, false, true, true><<<dim3(gx, 1), 256, 0, stream>>>(
        h3, nullptr, BT2r, b2, aggp, out, Nn, 64);
}

// Round 8
// 370.993 us; speedup vs baseline: 1.9850x; 1.9850x over previous
//
#include <hip/hip_runtime.h>

// ---------------------------------------------------------------------------
// GraphSAGE 3-layer, bf16 pipeline. Round 8 = round-4 base (374us) plus:
//   - agg256: 4 nodes/wave (16-lane groups, 32B/lane), unroll 2
//     -> 16 independent gather loads in flight per wave (was 4); no shuffles.
//   - fill_csr split: pos=atomicAdd (coalesced store) then col[pos]=src
//     (breaks atomic->store dependency chain).
//   - XCD-pinning experiments reverted (falsified in rounds 5/7).
// ---------------------------------------------------------------------------

typedef short bf16x8 __attribute__((ext_vector_type(8)));
typedef float f32x4 __attribute__((ext_vector_type(4)));

__device__ __forceinline__ unsigned short f2bf(float f) {
    unsigned int b = __float_as_uint(f);
    b += 0x7fffu + ((b >> 16) & 1u);
    return (unsigned short)(b >> 16);
}
__device__ __forceinline__ float bflo(unsigned int u) { return __uint_as_float(u << 16); }
__device__ __forceinline__ float bfhi(unsigned int u) { return __uint_as_float(u & 0xffff0000u); }

__device__ __forceinline__ void gload_lds16(const void* g, void* l) {
    __builtin_amdgcn_global_load_lds(
        (const __attribute__((address_space(1))) void*)g,
        (__attribute__((address_space(3))) void*)l, 16, 0, 0);
}

// ---------------- CSR build ----------------
__global__ void count_deg_kernel(const int* __restrict__ ei, int* __restrict__ deg, int E) {
    int e = blockIdx.x * blockDim.x + threadIdx.x;
    if (e < E) atomicAdd(&deg[ei[E + e]], 1);
}

__global__ __launch_bounds__(1024) void scan1_kernel(
        const int* __restrict__ deg, int* __restrict__ incl, int* __restrict__ bsum, int n) {
    __shared__ int wsum[16];
    __shared__ int woff[16];
    const int tid = threadIdx.x, lane = tid & 63, wid = tid >> 6;
    int i = blockIdx.x * 1024 + tid;
    int x = (i < n) ? deg[i] : 0;
    #pragma unroll
    for (int off = 1; off < 64; off <<= 1) {
        int t = __shfl_up(x, off, 64);
        if (lane >= off) x += t;
    }
    if (lane == 63) wsum[wid] = x;
    __syncthreads();
    if (tid == 0) {
        int s = 0;
        #pragma unroll
        for (int w = 0; w < 16; ++w) { woff[w] = s; s += wsum[w]; }
        bsum[blockIdx.x] = s;
    }
    __syncthreads();
    if (i < n) incl[i] = x + woff[wid];
}

__global__ void scan2_kernel(int* __restrict__ bsum, int nb) {
    int lane = threadIdx.x;
    int v = (lane < nb) ? bsum[lane] : 0;
    int x = v;
    #pragma unroll
    for (int off = 1; off < 64; off <<= 1) {
        int t = __shfl_up(x, off, 64);
        if (lane >= off) x += t;
    }
    if (lane < nb) bsum[lane] = x - v;   // exclusive
}

__global__ void scan3_kernel(const int* __restrict__ incl, const int* __restrict__ bsum,
                             int* __restrict__ row_ptr, int* __restrict__ cursor, int n) {
    int i = blockIdx.x * blockDim.x + threadIdx.x;
    if (i == 0) { row_ptr[0] = 0; cursor[0] = 0; }
    if (i < n) {
        int v = incl[i] + bsum[i >> 10];
        row_ptr[i + 1] = v;
        if (i + 1 < n) cursor[i + 1] = v;
    }
}

// fill, phase a: pos[e] = atomicAdd(cursor[dst[e]]) -- no dependent scatter
__global__ void fill_pos_kernel(const int* __restrict__ ei, int* __restrict__ cursor,
                                int* __restrict__ pos, int E) {
    int e = blockIdx.x * blockDim.x + threadIdx.x;
    if (e < E) pos[e] = atomicAdd(&cursor[ei[E + e]], 1);
}

// fill, phase b: independent scatter stores
__global__ void fill_scatter_kernel(const int* __restrict__ ei, const int* __restrict__ pos,
                                    int* __restrict__ col, int E) {
    int e = blockIdx.x * blockDim.x + threadIdx.x;
    if (e < E) col[pos[e]] = ei[e];
}

// ---------------- converts ----------------
__global__ void cvt_bf16_kernel(const float* __restrict__ x, unsigned short* __restrict__ y, int n4) {
    int i = blockIdx.x * blockDim.x + threadIdx.x;
    if (i < n4) {
        float4 v = ((const float4*)x)[i];
        ushort4 o;
        o.x = f2bf(v.x); o.y = f2bf(v.y); o.z = f2bf(v.z); o.w = f2bf(v.w);
        ((ushort4*)y)[i] = o;
    }
}

__global__ void build_bt_kernel(const float* __restrict__ Wl, const float* __restrict__ Wr,
                                unsigned short* __restrict__ BT, int N) {
    int id = blockIdx.x * blockDim.x + threadIdx.x;
    if (id >= N * 512) return;
    int k = id / N;
    int n = id - k * N;
    float v = (k < 256) ? Wl[(size_t)k * N + n] : Wr[(size_t)(k - 256) * N + n];
    BT[(size_t)n * 512 + k] = f2bf(v);
}

__global__ void build_bt1_kernel(const float* __restrict__ W, unsigned short* __restrict__ BT, int N) {
    int id = blockIdx.x * blockDim.x + threadIdx.x;
    if (id >= N * 256) return;
    int k = id / N;
    int n = id - k * N;
    BT[(size_t)n * 256 + k] = f2bf(W[(size_t)k * N + n]);
}

// ---------------- aggregation, 256-dim ----------------
// 4 nodes per wave: one 16-lane group per node; lane owns 16 features (32B).
// Per edge: 2 x uint4 loads/lane; unroll 2 edges -> per wave 16 independent
// 16B loads in flight. No cross-lane reduction (lanes own disjoint features).
__global__ __launch_bounds__(256) void aggregate256_kernel(
        const unsigned short* __restrict__ h, const int* __restrict__ row_ptr,
        const int* __restrict__ col, unsigned short* __restrict__ agg, int n) {
    const int wavei = threadIdx.x >> 6;            // 0..3
    const int lane = threadIdx.x & 63;
    const int grp = lane >> 4;                     // 0..3
    const int node = (blockIdx.x * 4 + wavei) * 4 + grp;
    if (node >= n) return;
    const int start = row_ptr[node], end = row_ptr[node + 1];
    const int fo = (lane & 15) * 16;               // 16 bf16 per lane
    float a[16];
    #pragma unroll
    for (int i = 0; i < 16; ++i) a[i] = 0.f;
    int e = start;
    for (; e + 2 <= end; e += 2) {
        const unsigned short* r0 = h + (size_t)col[e] * 256 + fo;
        const unsigned short* r1 = h + (size_t)col[e + 1] * 256 + fo;
        uint4 v00 = *(const uint4*)r0;
        uint4 v01 = *(const uint4*)(r0 + 8);
        uint4 v10 = *(const uint4*)r1;
        uint4 v11 = *(const uint4*)(r1 + 8);
        a[0]  += bflo(v00.x) + bflo(v10.x); a[1]  += bfhi(v00.x) + bfhi(v10.x);
        a[2]  += bflo(v00.y) + bflo(v10.y); a[3]  += bfhi(v00.y) + bfhi(v10.y);
        a[4]  += bflo(v00.z) + bflo(v10.z); a[5]  += bfhi(v00.z) + bfhi(v10.z);
        a[6]  += bflo(v00.w) + bflo(v10.w); a[7]  += bfhi(v00.w) + bfhi(v10.w);
        a[8]  += bflo(v01.x) + bflo(v11.x); a[9]  += bfhi(v01.x) + bfhi(v11.x);
        a[10] += bflo(v01.y) + bflo(v11.y); a[11] += bfhi(v01.y) + bfhi(v11.y);
        a[12] += bflo(v01.z) + bflo(v11.z); a[13] += bfhi(v01.z) + bfhi(v11.z);
        a[14] += bflo(v01.w) + bflo(v11.w); a[15] += bfhi(v01.w) + bfhi(v11.w);
    }
    if (e < end) {
        const unsigned short* r0 = h + (size_t)col[e] * 256 + fo;
        uint4 v00 = *(const uint4*)r0;
        uint4 v01 = *(const uint4*)(r0 + 8);
        a[0]  += bflo(v00.x); a[1]  += bfhi(v00.x);
        a[2]  += bflo(v00.y); a[3]  += bfhi(v00.y);
        a[4]  += bflo(v00.z); a[5]  += bfhi(v00.z);
        a[6]  += bflo(v00.w); a[7]  += bfhi(v00.w);
        a[8]  += bflo(v01.x); a[9]  += bfhi(v01.x);
        a[10] += bflo(v01.y); a[11] += bfhi(v01.y);
        a[12] += bflo(v01.z); a[13] += bfhi(v01.z);
        a[14] += bflo(v01.w); a[15] += bfhi(v01.w);
    }
    const int d = end - start;
    const float inv = 1.0f / (float)(d > 1 ? d : 1);
    uint4 o0, o1;
    o0.x = (unsigned)f2bf(a[0] * inv)  | ((unsigned)f2bf(a[1] * inv) << 16);
    o0.y = (unsigned)f2bf(a[2] * inv)  | ((unsigned)f2bf(a[3] * inv) << 16);
    o0.z = (unsigned)f2bf(a[4] * inv)  | ((unsigned)f2bf(a[5] * inv) << 16);
    o0.w = (unsigned)f2bf(a[6] * inv)  | ((unsigned)f2bf(a[7] * inv) << 16);
    o1.x = (unsigned)f2bf(a[8] * inv)  | ((unsigned)f2bf(a[9] * inv) << 16);
    o1.y = (unsigned)f2bf(a[10] * inv) | ((unsigned)f2bf(a[11] * inv) << 16);
    o1.z = (unsigned)f2bf(a[12] * inv) | ((unsigned)f2bf(a[13] * inv) << 16);
    o1.w = (unsigned)f2bf(a[14] * inv) | ((unsigned)f2bf(a[15] * inv) << 16);
    unsigned short* dst = agg + (size_t)node * 256 + fo;
    *(uint4*)dst = o0;
    *(uint4*)(dst + 8) = o1;
}

// ---------------- aggregation, 64-dim (bf16 in, fp32 out) ----------------
// one wave per node; 4 edges concurrently (16-lane groups), 8B/lane, unroll 2
__global__ __launch_bounds__(256) void aggregate64_kernel(
        const unsigned short* __restrict__ p, const int* __restrict__ row_ptr,
        const int* __restrict__ col, float* __restrict__ aggp, int n) {
    int node = blockIdx.x * 4 + (threadIdx.x >> 6);
    int lane = threadIdx.x & 63;
    if (node >= n) return;
    const int start = row_ptr[node], end = row_ptr[node + 1];
    const int g = lane >> 4;            // edge group 0..3
    const int fo = (lane & 15) * 4;     // 4 bf16 per lane
    float a0 = 0.f, a1 = 0.f, a2 = 0.f, a3 = 0.f;
    int eb = start;
    for (; eb + 8 <= end; eb += 8) {
        int e0 = eb + g, e1 = eb + 4 + g;
        uint2 v0 = *(const uint2*)(p + (size_t)col[e0] * 64 + fo);
        uint2 v1 = *(const uint2*)(p + (size_t)col[e1] * 64 + fo);
        a0 += bflo(v0.x) + bflo(v1.x); a1 += bfhi(v0.x) + bfhi(v1.x);
        a2 += bflo(v0.y) + bflo(v1.y); a3 += bfhi(v0.y) + bfhi(v1.y);
    }
    for (; eb < end; eb += 4) {
        int e = eb + g;
        if (e < end) {
            uint2 v = *(const uint2*)(p + (size_t)col[e] * 64 + fo);
            a0 += bflo(v.x); a1 += bfhi(v.x);
            a2 += bflo(v.y); a3 += bfhi(v.y);
        }
    }
    #pragma unroll
    for (int m = 16; m <= 32; m <<= 1) {
        a0 += __shfl_xor(a0, m, 64);
        a1 += __shfl_xor(a1, m, 64);
        a2 += __shfl_xor(a2, m, 64);
        a3 += __shfl_xor(a3, m, 64);
    }
    int d = end - start;
    float inv = 1.0f / (float)(d > 1 ? d : 1);
    if (lane < 16) {
        float4 o = make_float4(a0 * inv, a1 * inv, a2 * inv, a3 * inv);
        *(float4*)(aggp + (size_t)node * 64 + fo) = o;
    }
}

// ---------------- fused MFMA GEMM ----------------
// C = [A0|A1](M x NKS*32) @ BT^T (+bias) (+add) (+relu); BT is [Nc'][NKS*32] bf16.
// A rows are always 256-wide. BM=128, BN=NT*32, BK=32; 4 waves (2x2).
template<int NKS, int NT, bool RELU, bool OUT_BF16, bool HAS_BIAS, bool HAS_ADD>
__global__ __launch_bounds__(256) void gemm_mfma_kernel(
        const unsigned short* __restrict__ A0, const unsigned short* __restrict__ A1,
        const unsigned short* __restrict__ BT, const float* __restrict__ bias,
        const float* __restrict__ add, void* __restrict__ Cout, int M, int Nc) {
    constexpr int BN = NT * 32;
    constexpr int KB = NKS * 32;           // BT row stride (elems)
    __shared__ unsigned short As[128 * 32];
    __shared__ unsigned short Bs[BN * 32];
    const int tid = threadIdx.x;
    const int lane = tid & 63;
    const int wid = tid >> 6;
    const int wr = wid >> 1, wc = wid & 1;
    const int row0 = blockIdx.x * 128;
    const int col0 = blockIdx.y * BN;

    f32x4 acc[4][NT];
    #pragma unroll
    for (int i = 0; i < 4; ++i)
        #pragma unroll
        for (int j = 0; j < NT; ++j) acc[i][j] = (f32x4){0.f, 0.f, 0.f, 0.f};

    const int rA = tid >> 2;
    const int kc = (tid & 3) * 8;

    for (int ks = 0; ks < NKS; ++ks) {
        const unsigned short* Asrc = (NKS == 16) ? (ks < 8 ? A0 : A1) : A0;
        const int ka = (NKS == 16) ? ((ks & 7) * 32) : (ks * 32);
        #pragma unroll
        for (int i = 0; i < 2; ++i) {
            const unsigned short* g = Asrc + (size_t)(row0 + rA + i * 64) * 256 + ka + kc;
            gload_lds16(g, As + (size_t)i * 2048 + tid * 8);
        }
        #pragma unroll
        for (int i = 0; i < NT / 2; ++i) {
            const unsigned short* g = BT + (size_t)(col0 + rA + i * 64) * KB + ks * 32 + kc;
            gload_lds16(g, Bs + (size_t)i * 2048 + tid * 8);
        }
        __syncthreads();

        bf16x8 a[4], b[NT];
        #pragma unroll
        for (int tm = 0; tm < 4; ++tm)
            a[tm] = *(const bf16x8*)&As[(wr * 64 + tm * 16 + (lane & 15)) * 32 + (lane >> 4) * 8];
        #pragma unroll
        for (int tn = 0; tn < NT; ++tn)
            b[tn] = *(const bf16x8*)&Bs[(wc * NT * 16 + tn * 16 + (lane & 15)) * 32 + (lane >> 4) * 8];
        #pragma unroll
        for (int tm = 0; tm < 4; ++tm)
            #pragma unroll
            for (int tn = 0; tn < NT; ++tn)
                acc[tm][tn] = __builtin_amdgcn_mfma_f32_16x16x32_bf16(a[tm], b[tn], acc[tm][tn], 0, 0, 0);
        __syncthreads();
    }

    const int cb = col0 + wc * NT * 16;
    #pragma unroll
    for (int tn = 0; tn < NT; ++tn) {
        int colg = cb + tn * 16 + (lane & 15);
        float bv = HAS_BIAS ? bias[colg] : 0.f;
        #pragma unroll
        for (int tm = 0; tm < 4; ++tm) {
            #pragma unroll
            for (int r = 0; r < 4; ++r) {
                int row = row0 + wr * 64 + tm * 16 + (lane >> 4) * 4 + r;
                if (row < M) {
                    float v = acc[tm][tn][r] + bv;
                    if (HAS_ADD) v += add[(size_t)row * Nc + colg];
                    if (RELU) v = fmaxf(v, 0.f);
                    if (OUT_BF16)
                        ((unsigned short*)Cout)[(size_t)row * Nc + colg] = f2bf(v);
                    else
                        ((float*)Cout)[(size_t)row * Nc + colg] = v;
                }
            }
        }
    }
}

extern "C" void kernel_launch(void* const* d_in, const int* in_sizes, int n_in,
                              void* d_out, int out_size, void* d_ws, size_t ws_size,
                              hipStream_t stream) {
    const float* x   = (const float*)d_in[0];
    const int*   ei  = (const int*)d_in[1];
    const float* Wl0 = (const float*)d_in[2];
    const float* Wr0 = (const float*)d_in[3];
    const float* b0  = (const float*)d_in[4];
    const float* Wl1 = (const float*)d_in[5];
    const float* Wr1 = (const float*)d_in[6];
    const float* b1  = (const float*)d_in[7];
    const float* Wl2 = (const float*)d_in[8];
    const float* Wr2 = (const float*)d_in[9];
    const float* b2  = (const float*)d_in[10];
    float* out = (float*)d_out;

    const int Nn = in_sizes[0] / 256;          // 50000
    const int E  = in_sizes[1] / 2;            // 800000
    const int Mpad = ((Nn + 127) / 128) * 128; // 50048
    const int nb = (Nn + 1023) / 1024;         // scan blocks (49)

    char* ws = (char*)d_ws;
    size_t off = 0;
    auto take = [&](size_t bytes) -> void* {
        void* p = (void*)(ws + off);
        off += (bytes + 255) & ~(size_t)255;
        return p;
    };
    int* deg     = (int*)take((size_t)Nn * 4);
    int* incl    = (int*)take((size_t)Nn * 4);
    int* bsum    = (int*)take((size_t)64 * 4);
    int* row_ptr = (int*)take((size_t)(Nn + 1) * 4);
    int* cursor  = (int*)take((size_t)Nn * 4);
    int* col     = (int*)take((size_t)E * 4);
    int* pos     = (int*)take((size_t)E * 4);
    unsigned short* xb  = (unsigned short*)take((size_t)Mpad * 256 * 2);
    unsigned short* h1  = (unsigned short*)take((size_t)Mpad * 256 * 2);
    unsigned short* h2  = (unsigned short*)take((size_t)Mpad * 256 * 2);
    unsigned short* h3  = (unsigned short*)take((size_t)Mpad * 256 * 2);
    unsigned short* p2  = (unsigned short*)take((size_t)Mpad * 64 * 2);
    float* aggp = (float*)take((size_t)Mpad * 64 * 4);
    unsigned short* BT0  = (unsigned short*)take((size_t)256 * 512 * 2);
    unsigned short* BT1  = (unsigned short*)take((size_t)256 * 512 * 2);
    unsigned short* BT2l = (unsigned short*)take((size_t)64 * 256 * 2);
    unsigned short* BT2r = (unsigned short*)take((size_t)64 * 256 * 2);
    (void)ws_size; (void)n_in; (void)out_size;

    // ---- CSR build ----
    hipMemsetAsync(deg, 0, (size_t)Nn * 4, stream);
    count_deg_kernel<<<(E + 255) / 256, 256, 0, stream>>>(ei, deg, E);
    scan1_kernel<<<nb, 1024, 0, stream>>>(deg, incl, bsum, Nn);
    scan2_kernel<<<1, 64, 0, stream>>>(bsum, nb);
    scan3_kernel<<<(Nn + 255) / 256, 256, 0, stream>>>(incl, bsum, row_ptr, cursor, Nn);
    fill_pos_kernel<<<(E + 255) / 256, 256, 0, stream>>>(ei, cursor, pos, E);
    fill_scatter_kernel<<<(E + 255) / 256, 256, 0, stream>>>(ei, pos, col, E);

    // ---- converts ----
    cvt_bf16_kernel<<<(Nn * 64 + 255) / 256, 256, 0, stream>>>(x, xb, Nn * 64);
    build_bt_kernel<<<(256 * 512 + 255) / 256, 256, 0, stream>>>(Wl0, Wr0, BT0, 256);
    build_bt_kernel<<<(256 * 512 + 255) / 256, 256, 0, stream>>>(Wl1, Wr1, BT1, 256);
    build_bt1_kernel<<<(64 * 256 + 255) / 256, 256, 0, stream>>>(Wl2, BT2l, 64);
    build_bt1_kernel<<<(64 * 256 + 255) / 256, 256, 0, stream>>>(Wr2, BT2r, 64);

    const int gx = Mpad / 128;
    const int aggGrid256 = (Nn + 15) / 16;   // 16 nodes per block (4 waves x 4 groups)
    const int aggGrid64  = (Nn + 3) / 4;     // 4 nodes per block (1 wave each)

    // ---- layer 0 ----
    aggregate256_kernel<<<aggGrid256, 256, 0, stream>>>(xb, row_ptr, col, h1, Nn);
    gemm_mfma_kernel<16, 4, true, true, true, false><<<dim3(gx, 2), 256, 0, stream>>>(
        h1, xb, BT0, b0, nullptr, h2, Nn, 256);
    // ---- layer 1 ----
    aggregate256_kernel<<<aggGrid256, 256, 0, stream>>>(h2, row_ptr, col, h1, Nn);
    gemm_mfma_kernel<16, 4, true, true, true, false><<<dim3(gx, 2), 256, 0, stream>>>(
        h1, h2, BT1, b1, nullptr, h3, Nn, 256);
    // ---- layer 2: agg(h3)@Wl2 == agg(h3@Wl2) ----
    gemm_mfma_kernel<8, 2, false, true, false, false><<<dim3(gx, 1), 256, 0, stream>>>(
        h3, nullptr, BT2l, nullptr, nullptr, p2, Nn, 64);
    aggregate64_kernel<<<aggGrid64, 256, 0, stream>>>(p2, row_ptr, col, aggp, Nn);
    gemm_mfma_kernel<8, 2, false, false, true, true><<<dim3(gx, 1), 256, 0, stream>>>(
        h3, nullptr, BT2r, b2, aggp, out, Nn, 64);
}

// Round 9
// 318.378 us; speedup vs baseline: 2.3130x; 1.1653x over previous
//
#include <hip/hip_runtime.h>

// ---------------------------------------------------------------------------
// GraphSAGE 3-layer, bf16 pipeline. Round 9:
//   - agg256 reverted to round-4 structure (measured best, 55.5us; structural
//     floor ~3.4 TB/s L2-miss path confirmed over 3 variants).
//   - CSR: count_deg eliminated (fill_pos's atomicAdd IS the count);
//     scatter uses row_ptr[d]+pos[e].
//   - GEMM layers 0/1: BN=256 (NT=8, single y-block) -> half the A refetch,
//     half the blocks. launch_bounds(256,2).
//   - layer 2 keeps agg(h@Wl2) reorder (64-dim gathers).
// ---------------------------------------------------------------------------

typedef short bf16x8 __attribute__((ext_vector_type(8)));
typedef float f32x4 __attribute__((ext_vector_type(4)));

__device__ __forceinline__ unsigned short f2bf(float f) {
    unsigned int b = __float_as_uint(f);
    b += 0x7fffu + ((b >> 16) & 1u);
    return (unsigned short)(b >> 16);
}
__device__ __forceinline__ float bflo(unsigned int u) { return __uint_as_float(u << 16); }
__device__ __forceinline__ float bfhi(unsigned int u) { return __uint_as_float(u & 0xffff0000u); }

__device__ __forceinline__ void gload_lds16(const void* g, void* l) {
    __builtin_amdgcn_global_load_lds(
        (const __attribute__((address_space(1))) void*)g,
        (__attribute__((address_space(3))) void*)l, 16, 0, 0);
}

// ---------------- CSR build ----------------
// phase a: pos[e] = within-dst rank; cursor ends holding deg[dst]
__global__ void fill_pos_kernel(const int* __restrict__ ei, int* __restrict__ cursor,
                                int* __restrict__ pos, int E) {
    int e = blockIdx.x * blockDim.x + threadIdx.x;
    if (e < E) pos[e] = atomicAdd(&cursor[ei[E + e]], 1);
}

__global__ __launch_bounds__(1024) void scan1_kernel(
        const int* __restrict__ deg, int* __restrict__ incl, int* __restrict__ bsum, int n) {
    __shared__ int wsum[16];
    __shared__ int woff[16];
    const int tid = threadIdx.x, lane = tid & 63, wid = tid >> 6;
    int i = blockIdx.x * 1024 + tid;
    int x = (i < n) ? deg[i] : 0;
    #pragma unroll
    for (int off = 1; off < 64; off <<= 1) {
        int t = __shfl_up(x, off, 64);
        if (lane >= off) x += t;
    }
    if (lane == 63) wsum[wid] = x;
    __syncthreads();
    if (tid == 0) {
        int s = 0;
        #pragma unroll
        for (int w = 0; w < 16; ++w) { woff[w] = s; s += wsum[w]; }
        bsum[blockIdx.x] = s;
    }
    __syncthreads();
    if (i < n) incl[i] = x + woff[wid];
}

__global__ void scan2_kernel(int* __restrict__ bsum, int nb) {
    int lane = threadIdx.x;
    int v = (lane < nb) ? bsum[lane] : 0;
    int x = v;
    #pragma unroll
    for (int off = 1; off < 64; off <<= 1) {
        int t = __shfl_up(x, off, 64);
        if (lane >= off) x += t;
    }
    if (lane < nb) bsum[lane] = x - v;   // exclusive
}

__global__ void scan3_kernel(const int* __restrict__ incl, const int* __restrict__ bsum,
                             int* __restrict__ row_ptr, int n) {
    int i = blockIdx.x * blockDim.x + threadIdx.x;
    if (i == 0) row_ptr[0] = 0;
    if (i < n) row_ptr[i + 1] = incl[i] + bsum[i >> 10];
}

// phase b: col[row_ptr[d] + pos[e]] = src
__global__ void fill_scatter_kernel(const int* __restrict__ ei, const int* __restrict__ pos,
                                    const int* __restrict__ row_ptr, int* __restrict__ col, int E) {
    int e = blockIdx.x * blockDim.x + threadIdx.x;
    if (e < E) {
        int d = ei[E + e];
        col[row_ptr[d] + pos[e]] = ei[e];
    }
}

// ---------------- converts ----------------
__global__ void cvt_bf16_kernel(const float* __restrict__ x, unsigned short* __restrict__ y, int n4) {
    int i = blockIdx.x * blockDim.x + threadIdx.x;
    if (i < n4) {
        float4 v = ((const float4*)x)[i];
        ushort4 o;
        o.x = f2bf(v.x); o.y = f2bf(v.y); o.z = f2bf(v.z); o.w = f2bf(v.w);
        ((ushort4*)y)[i] = o;
    }
}

__global__ void build_bt_kernel(const float* __restrict__ Wl, const float* __restrict__ Wr,
                                unsigned short* __restrict__ BT, int N) {
    int id = blockIdx.x * blockDim.x + threadIdx.x;
    if (id >= N * 512) return;
    int k = id / N;
    int n = id - k * N;
    float v = (k < 256) ? Wl[(size_t)k * N + n] : Wr[(size_t)(k - 256) * N + n];
    BT[(size_t)n * 512 + k] = f2bf(v);
}

__global__ void build_bt1_kernel(const float* __restrict__ W, unsigned short* __restrict__ BT, int N) {
    int id = blockIdx.x * blockDim.x + threadIdx.x;
    if (id >= N * 256) return;
    int k = id / N;
    int n = id - k * N;
    BT[(size_t)n * 256 + k] = f2bf(W[(size_t)k * N + n]);
}

// ---------------- aggregation, 256-dim (round-4 structure) ----------------
// one wave per node; 2 edges concurrently (half-waves), 16B/lane, unroll 2
__global__ __launch_bounds__(256) void aggregate256_kernel(
        const unsigned short* __restrict__ h, const int* __restrict__ row_ptr,
        const int* __restrict__ col, unsigned short* __restrict__ agg, int n) {
    int node = blockIdx.x * 4 + (threadIdx.x >> 6);
    int lane = threadIdx.x & 63;
    if (node >= n) return;
    const int start = row_ptr[node], end = row_ptr[node + 1];
    const int half = lane >> 5;
    const int fo = (lane & 31) * 8;     // 8 bf16 per lane
    float a[8] = {0.f, 0.f, 0.f, 0.f, 0.f, 0.f, 0.f, 0.f};
    int eb = start;
    for (; eb + 4 <= end; eb += 4) {
        int e0 = eb + half, e1 = eb + 2 + half;
        uint4 v0 = *(const uint4*)(h + (size_t)col[e0] * 256 + fo);
        uint4 v1 = *(const uint4*)(h + (size_t)col[e1] * 256 + fo);
        a[0] += bflo(v0.x) + bflo(v1.x); a[1] += bfhi(v0.x) + bfhi(v1.x);
        a[2] += bflo(v0.y) + bflo(v1.y); a[3] += bfhi(v0.y) + bfhi(v1.y);
        a[4] += bflo(v0.z) + bflo(v1.z); a[5] += bfhi(v0.z) + bfhi(v1.z);
        a[6] += bflo(v0.w) + bflo(v1.w); a[7] += bfhi(v0.w) + bfhi(v1.w);
    }
    for (; eb < end; eb += 2) {
        int e = eb + half;
        if (e < end) {
            uint4 v = *(const uint4*)(h + (size_t)col[e] * 256 + fo);
            a[0] += bflo(v.x); a[1] += bfhi(v.x);
            a[2] += bflo(v.y); a[3] += bfhi(v.y);
            a[4] += bflo(v.z); a[5] += bfhi(v.z);
            a[6] += bflo(v.w); a[7] += bfhi(v.w);
        }
    }
    #pragma unroll
    for (int i = 0; i < 8; ++i) a[i] += __shfl_xor(a[i], 32, 64);
    int d = end - start;
    float inv = 1.0f / (float)(d > 1 ? d : 1);
    if (lane < 32) {
        ushort4 o0, o1;
        o0.x = f2bf(a[0] * inv); o0.y = f2bf(a[1] * inv);
        o0.z = f2bf(a[2] * inv); o0.w = f2bf(a[3] * inv);
        o1.x = f2bf(a[4] * inv); o1.y = f2bf(a[5] * inv);
        o1.z = f2bf(a[6] * inv); o1.w = f2bf(a[7] * inv);
        *(ushort4*)(agg + (size_t)node * 256 + fo) = o0;
        *(ushort4*)(agg + (size_t)node * 256 + fo + 4) = o1;
    }
}

// ---------------- aggregation, 64-dim (bf16 in, fp32 out) ----------------
__global__ __launch_bounds__(256) void aggregate64_kernel(
        const unsigned short* __restrict__ p, const int* __restrict__ row_ptr,
        const int* __restrict__ col, float* __restrict__ aggp, int n) {
    int node = blockIdx.x * 4 + (threadIdx.x >> 6);
    int lane = threadIdx.x & 63;
    if (node >= n) return;
    const int start = row_ptr[node], end = row_ptr[node + 1];
    const int g = lane >> 4;            // edge group 0..3
    const int fo = (lane & 15) * 4;     // 4 bf16 per lane
    float a0 = 0.f, a1 = 0.f, a2 = 0.f, a3 = 0.f;
    int eb = start;
    for (; eb + 8 <= end; eb += 8) {
        int e0 = eb + g, e1 = eb + 4 + g;
        uint2 v0 = *(const uint2*)(p + (size_t)col[e0] * 64 + fo);
        uint2 v1 = *(const uint2*)(p + (size_t)col[e1] * 64 + fo);
        a0 += bflo(v0.x) + bflo(v1.x); a1 += bfhi(v0.x) + bfhi(v1.x);
        a2 += bflo(v0.y) + bflo(v1.y); a3 += bfhi(v0.y) + bfhi(v1.y);
    }
    for (; eb < end; eb += 4) {
        int e = eb + g;
        if (e < end) {
            uint2 v = *(const uint2*)(p + (size_t)col[e] * 64 + fo);
            a0 += bflo(v.x); a1 += bfhi(v.x);
            a2 += bflo(v.y); a3 += bfhi(v.y);
        }
    }
    #pragma unroll
    for (int m = 16; m <= 32; m <<= 1) {
        a0 += __shfl_xor(a0, m, 64);
        a1 += __shfl_xor(a1, m, 64);
        a2 += __shfl_xor(a2, m, 64);
        a3 += __shfl_xor(a3, m, 64);
    }
    int d = end - start;
    float inv = 1.0f / (float)(d > 1 ? d : 1);
    if (lane < 16) {
        float4 o = make_float4(a0 * inv, a1 * inv, a2 * inv, a3 * inv);
        *(float4*)(aggp + (size_t)node * 64 + fo) = o;
    }
}

// ---------------- fused MFMA GEMM ----------------
// C = [A0|A1](M x NKS*32) @ BT^T (+bias) (+add) (+relu); BT is [Nc'][NKS*32] bf16.
// A rows are always 256-wide. BM=128, BN=NT*32, BK=32; 4 waves (2x2).
template<int NKS, int NT, bool RELU, bool OUT_BF16, bool HAS_BIAS, bool HAS_ADD>
__global__ __launch_bounds__(256, 2) void gemm_mfma_kernel(
        const unsigned short* __restrict__ A0, const unsigned short* __restrict__ A1,
        const unsigned short* __restrict__ BT, const float* __restrict__ bias,
        const float* __restrict__ add, void* __restrict__ Cout, int M, int Nc) {
    constexpr int BN = NT * 32;
    constexpr int KB = NKS * 32;           // BT row stride (elems)
    __shared__ unsigned short As[128 * 32];
    __shared__ unsigned short Bs[BN * 32];
    const int tid = threadIdx.x;
    const int lane = tid & 63;
    const int wid = tid >> 6;
    const int wr = wid >> 1, wc = wid & 1;
    const int row0 = blockIdx.x * 128;
    const int col0 = blockIdx.y * BN;

    f32x4 acc[4][NT];
    #pragma unroll
    for (int i = 0; i < 4; ++i)
        #pragma unroll
        for (int j = 0; j < NT; ++j) acc[i][j] = (f32x4){0.f, 0.f, 0.f, 0.f};

    const int rA = tid >> 2;
    const int kc = (tid & 3) * 8;

    for (int ks = 0; ks < NKS; ++ks) {
        const unsigned short* Asrc = (NKS == 16) ? (ks < 8 ? A0 : A1) : A0;
        const int ka = (NKS == 16) ? ((ks & 7) * 32) : (ks * 32);
        #pragma unroll
        for (int i = 0; i < 2; ++i) {
            const unsigned short* g = Asrc + (size_t)(row0 + rA + i * 64) * 256 + ka + kc;
            gload_lds16(g, As + (size_t)i * 2048 + tid * 8);
        }
        #pragma unroll
        for (int i = 0; i < NT / 2; ++i) {
            const unsigned short* g = BT + (size_t)(col0 + rA + i * 64) * KB + ks * 32 + kc;
            gload_lds16(g, Bs + (size_t)i * 2048 + tid * 8);
        }
        __syncthreads();

        bf16x8 a[4], b[NT];
        #pragma unroll
        for (int tm = 0; tm < 4; ++tm)
            a[tm] = *(const bf16x8*)&As[(wr * 64 + tm * 16 + (lane & 15)) * 32 + (lane >> 4) * 8];
        #pragma unroll
        for (int tn = 0; tn < NT; ++tn)
            b[tn] = *(const bf16x8*)&Bs[(wc * NT * 16 + tn * 16 + (lane & 15)) * 32 + (lane >> 4) * 8];
        #pragma unroll
        for (int tm = 0; tm < 4; ++tm)
            #pragma unroll
            for (int tn = 0; tn < NT; ++tn)
                acc[tm][tn] = __builtin_amdgcn_mfma_f32_16x16x32_bf16(a[tm], b[tn], acc[tm][tn], 0, 0, 0);
        __syncthreads();
    }

    const int cb = col0 + wc * NT * 16;
    #pragma unroll
    for (int tn = 0; tn < NT; ++tn) {
        int colg = cb + tn * 16 + (lane & 15);
        float bv = HAS_BIAS ? bias[colg] : 0.f;
        #pragma unroll
        for (int tm = 0; tm < 4; ++tm) {
            #pragma unroll
            for (int r = 0; r < 4; ++r) {
                int row = row0 + wr * 64 + tm * 16 + (lane >> 4) * 4 + r;
                if (row < M) {
                    float v = acc[tm][tn][r] + bv;
                    if (HAS_ADD) v += add[(size_t)row * Nc + colg];
                    if (RELU) v = fmaxf(v, 0.f);
                    if (OUT_BF16)
                        ((unsigned short*)Cout)[(size_t)row * Nc + colg] = f2bf(v);
                    else
                        ((float*)Cout)[(size_t)row * Nc + colg] = v;
                }
            }
        }
    }
}

extern "C" void kernel_launch(void* const* d_in, const int* in_sizes, int n_in,
                              void* d_out, int out_size, void* d_ws, size_t ws_size,
                              hipStream_t stream) {
    const float* x   = (const float*)d_in[0];
    const int*   ei  = (const int*)d_in[1];
    const float* Wl0 = (const float*)d_in[2];
    const float* Wr0 = (const float*)d_in[3];
    const float* b0  = (const float*)d_in[4];
    const float* Wl1 = (const float*)d_in[5];
    const float* Wr1 = (const float*)d_in[6];
    const float* b1  = (const float*)d_in[7];
    const float* Wl2 = (const float*)d_in[8];
    const float* Wr2 = (const float*)d_in[9];
    const float* b2  = (const float*)d_in[10];
    float* out = (float*)d_out;

    const int Nn = in_sizes[0] / 256;          // 50000
    const int E  = in_sizes[1] / 2;            // 800000
    const int Mpad = ((Nn + 127) / 128) * 128; // 50048
    const int nb = (Nn + 1023) / 1024;         // scan blocks (49)

    char* ws = (char*)d_ws;
    size_t off = 0;
    auto take = [&](size_t bytes) -> void* {
        void* p = (void*)(ws + off);
        off += (bytes + 255) & ~(size_t)255;
        return p;
    };
    int* cursor  = (int*)take((size_t)Nn * 4);      // deg after fill_pos
    int* incl    = (int*)take((size_t)Nn * 4);
    int* bsum    = (int*)take((size_t)64 * 4);
    int* row_ptr = (int*)take((size_t)(Nn + 1) * 4);
    int* col     = (int*)take((size_t)E * 4);
    int* pos     = (int*)take((size_t)E * 4);
    unsigned short* xb  = (unsigned short*)take((size_t)Mpad * 256 * 2);
    unsigned short* h1  = (unsigned short*)take((size_t)Mpad * 256 * 2);
    unsigned short* h2  = (unsigned short*)take((size_t)Mpad * 256 * 2);
    unsigned short* h3  = (unsigned short*)take((size_t)Mpad * 256 * 2);
    unsigned short* p2  = (unsigned short*)take((size_t)Mpad * 64 * 2);
    float* aggp = (float*)take((size_t)Mpad * 64 * 4);
    unsigned short* BT0  = (unsigned short*)take((size_t)256 * 512 * 2);
    unsigned short* BT1  = (unsigned short*)take((size_t)256 * 512 * 2);
    unsigned short* BT2l = (unsigned short*)take((size_t)64 * 256 * 2);
    unsigned short* BT2r = (unsigned short*)take((size_t)64 * 256 * 2);
    (void)ws_size; (void)n_in; (void)out_size;

    // ---- CSR build (no count pass: fill_pos IS the count) ----
    hipMemsetAsync(cursor, 0, (size_t)Nn * 4, stream);
    fill_pos_kernel<<<(E + 255) / 256, 256, 0, stream>>>(ei, cursor, pos, E);
    scan1_kernel<<<nb, 1024, 0, stream>>>(cursor, incl, bsum, Nn);
    scan2_kernel<<<1, 64, 0, stream>>>(bsum, nb);
    scan3_kernel<<<(Nn + 255) / 256, 256, 0, stream>>>(incl, bsum, row_ptr, Nn);
    fill_scatter_kernel<<<(E + 255) / 256, 256, 0, stream>>>(ei, pos, row_ptr, col, E);

    // ---- converts ----
    cvt_bf16_kernel<<<(Nn * 64 + 255) / 256, 256, 0, stream>>>(x, xb, Nn * 64);
    build_bt_kernel<<<(256 * 512 + 255) / 256, 256, 0, stream>>>(Wl0, Wr0, BT0, 256);
    build_bt_kernel<<<(256 * 512 + 255) / 256, 256, 0, stream>>>(Wl1, Wr1, BT1, 256);
    build_bt1_kernel<<<(64 * 256 + 255) / 256, 256, 0, stream>>>(Wl2, BT2l, 64);
    build_bt1_kernel<<<(64 * 256 + 255) / 256, 256, 0, stream>>>(Wr2, BT2r, 64);

    const int gx = Mpad / 128;
    const int aggGrid = (Nn + 3) / 4;

    // ---- layer 0 ----
    aggregate256_kernel<<<aggGrid, 256, 0, stream>>>(xb, row_ptr, col, h1, Nn);
    gemm_mfma_kernel<16, 8, true, true, true, false><<<dim3(gx, 1), 256, 0, stream>>>(
        h1, xb, BT0, b0, nullptr, h2, Nn, 256);
    // ---- layer 1 ----
    aggregate256_kernel<<<aggGrid, 256, 0, stream>>>(h2, row_ptr, col, h1, Nn);
    gemm_mfma_kernel<16, 8, true, true, true, false><<<dim3(gx, 1), 256, 0, stream>>>(
        h1, h2, BT1, b1, nullptr, h3, Nn, 256);
    // ---- layer 2: agg(h3)@Wl2 == agg(h3@Wl2) ----
    gemm_mfma_kernel<8, 2, false, true, false, false><<<dim3(gx, 1), 256, 0, stream>>>(
        h3, nullptr, BT2l, nullptr, nullptr, p2, Nn, 64);
    aggregate64_kernel<<<aggGrid, 256, 0, stream>>>(p2, row_ptr, col, aggp, Nn);
    gemm_mfma_kernel<8, 2, false, false, true, true><<<dim3(gx, 1), 256, 0, stream>>>(
        h3, nullptr, BT2r, b2, aggp, out, Nn, 64);
}